// Round 6
// baseline (813.006 us; speedup 1.0000x reference)
//
#include <hip/hip_runtime.h>
#include <math.h>

// ---------- helpers ----------
__device__ __forceinline__ float lrelu(float v) { return v > 0.f ? v : 0.2f * v; }
__device__ __forceinline__ float bf2f(ushort u) {
    return __uint_as_float(((unsigned int)u) << 16);
}
__device__ __forceinline__ ushort f2bf(float f) {
    unsigned int x = __float_as_uint(f);
    return (ushort)((x + 0x7fffu + ((x >> 16) & 1u)) >> 16);
}
__device__ __forceinline__ float wave_allred_sum(float v) {
#pragma unroll
    for (int off = 1; off < 64; off <<= 1) v += __shfl_xor(v, off, 64);
    return v;
}

typedef short bf16x8 __attribute__((ext_vector_type(8)));
typedef float f32x4 __attribute__((ext_vector_type(4)));
typedef ushort u16x8 __attribute__((ext_vector_type(8)));

typedef const __attribute__((address_space(1))) void* gas_ptr;
typedef __attribute__((address_space(3))) void* las_ptr;
__device__ __forceinline__ void gload_lds16(const void* g, void* l) {
    __builtin_amdgcn_global_load_lds((gas_ptr)g, (las_ptr)l, 16, 0, 0);
}

// ---------- CSR build ----------
__global__ void hist_kernel(const int* __restrict__ dstrow, int* __restrict__ cnt,
                            int Etot, int E) {
    int i = blockIdx.x * blockDim.x + threadIdx.x;
    if (i >= Etot) return;
    int d = (i < E) ? dstrow[i] : (i - E);
    atomicAdd(&cnt[d], 1);
}

__global__ __launch_bounds__(256) void scan1_kernel(const int* __restrict__ cnt,
                                                    int* __restrict__ out,
                                                    int* __restrict__ btot, int n) {
    __shared__ int s[256];
    int i = blockIdx.x * 256 + threadIdx.x;
    int v = (i < n) ? cnt[i] : 0;
    s[threadIdx.x] = v;
    __syncthreads();
    for (int off = 1; off < 256; off <<= 1) {
        int t = (threadIdx.x >= off) ? s[threadIdx.x - off] : 0;
        __syncthreads();
        s[threadIdx.x] += t;
        __syncthreads();
    }
    if (i < n) out[i] = s[threadIdx.x];
    if (threadIdx.x == 255) btot[blockIdx.x] = s[255];
}
__global__ __launch_bounds__(1024) void scan2_kernel(int* __restrict__ btot, int nb) {
    __shared__ int s[1024];
    int tid = threadIdx.x;
    int v = (tid < nb) ? btot[tid] : 0;
    s[tid] = v;
    __syncthreads();
    for (int off = 1; off < 1024; off <<= 1) {
        int t = (tid >= off) ? s[tid - off] : 0;
        __syncthreads();
        s[tid] += t;
        __syncthreads();
    }
    if (tid < nb) btot[tid] = s[tid] - v;  // exclusive
}
__global__ void scan3_kernel(const int* __restrict__ scanned, const int* __restrict__ btot,
                             int* __restrict__ rowptr, int n) {
    int i = blockIdx.x * 256 + threadIdx.x;
    if (i < n) rowptr[i + 1] = scanned[i] + btot[i >> 8];
    if (i == 0) rowptr[0] = 0;
}

__global__ void fill_kernel(const int* __restrict__ srcrow, const int* __restrict__ dstrow,
                            const int* __restrict__ rowptr, int* __restrict__ pos,
                            int* __restrict__ srcs, int Etot, int E) {
    int i = blockIdx.x * blockDim.x + threadIdx.x;
    if (i >= Etot) return;
    int d = (i < E) ? dstrow[i] : (i - E);
    int s = (i < E) ? srcrow[i] : (i - E);
    int p = atomicAdd(&pos[d], 1);
    srcs[rowptr[d] + p] = s;
}

// ---------- weight pre-transpose: W[K][N] f32 -> Wt[N][K] bf16 ----------
__global__ __launch_bounds__(256) void wconv_kernel(const float* __restrict__ W,
                                                    ushort* __restrict__ Wt, int K, int N) {
    __shared__ float t[32][33];
    int k0 = blockIdx.x * 32, n0 = blockIdx.y * 32;
    int tx = threadIdx.x & 31, ty = threadIdx.x >> 5;  // ty: 0..7
#pragma unroll
    for (int i = 0; i < 32; i += 8)
        t[ty + i][tx] = W[(size_t)(k0 + ty + i) * N + n0 + tx];
    __syncthreads();
#pragma unroll
    for (int i = 0; i < 32; i += 8)
        Wt[(size_t)(n0 + ty + i) * K + k0 + tx] = f2bf(t[tx][ty + i]);
}

// ---------- MFMA GEMM (round-1 verified): C[M,N](bf16) = A @ Wt[N,K](bf16) ----------
template <typename TA>
__global__ __launch_bounds__(256) void gemm_mfma2(const TA* __restrict__ A,
                                                  const ushort* __restrict__ Wt,
                                                  ushort* __restrict__ C,
                                                  int M, int K, int N) {
    constexpr bool F32A = (sizeof(TA) == 4);
    constexpr int ASZ = F32A ? 16384 : 8192;  // per-buffer A bytes
    __shared__ __align__(16) unsigned char smem[2 * ASZ + 16384];

    int tid = threadIdx.x;
    int wv = tid >> 6, lane = tid & 63;
    int quad = lane >> 4, mrow = lane & 15;

    // bijective XCD-chunk swizzle (m204)
    int nwg = gridDim.x * gridDim.y;
    int id = blockIdx.y * gridDim.x + blockIdx.x;
    int q8 = nwg >> 3, r8 = nwg & 7;
    int xcd = id & 7, loc = id >> 3;
    int wgid = (xcd < r8 ? xcd * (q8 + 1) : r8 * (q8 + 1) + (xcd - r8) * q8) + loc;
    int n0 = (wgid % gridDim.x) * 128;
    int m0 = (wgid / gridDim.x) * 128;

    f32x4 acc[2][8] = {};

    auto stageA = [&](int kt, int buf) {
        unsigned char* lb = smem + buf * ASZ;
        if constexpr (F32A) {
#pragma unroll
            for (int q = 0; q < 4; q++) {
                int row = q * 32 + (tid >> 3);
                int gch = (tid & 7) ^ (row & 7);
                int rc = min(m0 + row, M - 1);
                gload_lds16((const float*)A + (size_t)rc * K + kt + gch * 4,
                            lb + q * 4096 + tid * 16);
            }
        } else {
#pragma unroll
            for (int q = 0; q < 2; q++) {
                int row = q * 64 + (tid >> 2);
                int gch = (tid & 3) ^ ((row & 3) ^ ((row >> 2) & 1));
                int rc = min(m0 + row, M - 1);
                gload_lds16((const ushort*)A + (size_t)rc * K + kt + gch * 8,
                            lb + q * 4096 + tid * 16);
            }
        }
    };
    auto stageB = [&](int kt, int buf) {
        unsigned char* lb = smem + 2 * ASZ + buf * 8192;
#pragma unroll
        for (int q = 0; q < 2; q++) {
            int row = q * 64 + (tid >> 2);
            int gch = (tid & 3) ^ ((row & 3) ^ ((row >> 2) & 1));
            gload_lds16(Wt + (size_t)(n0 + row) * K + kt + gch * 8,
                        lb + q * 4096 + tid * 16);
        }
    };

    int nsteps = K >> 5;
    stageA(0, 0);
    stageB(0, 0);
    __syncthreads();

    for (int s = 0; s < nsteps; s++) {
        int kt = s << 5;
        if (s + 1 < nsteps) {
            stageA(kt + 32, (s + 1) & 1);
            stageB(kt + 32, (s + 1) & 1);
        }
        const unsigned char* la = smem + (s & 1) * ASZ;
        const unsigned char* lbB = smem + 2 * ASZ + (s & 1) * 8192;

        bf16x8 afrag[2], bfrag[8];
#pragma unroll
        for (int r = 0; r < 2; r++) {
            int row = wv * 32 + r * 16 + mrow;
            if constexpr (F32A) {
                int f = row & 7;
                float4 x0 = *(const float4*)(la + row * 128 + ((quad * 2 + 0) ^ f) * 16);
                float4 x1 = *(const float4*)(la + row * 128 + ((quad * 2 + 1) ^ f) * 16);
                union { bf16x8 v; ushort u[8]; } t;
                t.u[0] = f2bf(x0.x); t.u[1] = f2bf(x0.y);
                t.u[2] = f2bf(x0.z); t.u[3] = f2bf(x0.w);
                t.u[4] = f2bf(x1.x); t.u[5] = f2bf(x1.y);
                t.u[6] = f2bf(x1.z); t.u[7] = f2bf(x1.w);
                afrag[r] = t.v;
            } else {
                int f = (row & 3) ^ ((row >> 2) & 1);
                afrag[r] = *(const bf16x8*)(la + row * 64 + (quad ^ f) * 16);
            }
        }
#pragma unroll
        for (int c = 0; c < 8; c++) {
            int row = c * 16 + mrow;
            int f = (row & 3) ^ ((row >> 2) & 1);
            bfrag[c] = *(const bf16x8*)(lbB + row * 64 + (quad ^ f) * 16);
        }
#pragma unroll
        for (int r = 0; r < 2; r++)
#pragma unroll
            for (int c = 0; c < 8; c++)
                acc[r][c] = __builtin_amdgcn_mfma_f32_16x16x32_bf16(afrag[r], bfrag[c],
                                                                    acc[r][c], 0, 0, 0);
        __syncthreads();
    }

    int col = lane & 15;
#pragma unroll
    for (int r = 0; r < 2; r++) {
#pragma unroll
        for (int c = 0; c < 8; c++) {
#pragma unroll
            for (int reg = 0; reg < 4; reg++) {
                int gm = m0 + wv * 32 + r * 16 + quad * 4 + reg;
                int gn = n0 + c * 16 + col;
                if (gm < M) C[(size_t)gm * N + gn] = f2bf(acc[r][c][reg]);
            }
        }
    }
}

// ---------- attention logits: one wave per node, bf16 H ----------
template <int VPL>
__global__ __launch_bounds__(256) void attn_wave(const ushort* __restrict__ H,
                                                 const float* __restrict__ asrc,
                                                 const float* __restrict__ adst,
                                                 float* __restrict__ es, float* __restrict__ ed,
                                                 int N) {
    constexpr int HC = VPL * 64;
    int lane = threadIdx.x & 63;
    int node = (blockIdx.x * blockDim.x + threadIdx.x) >> 6;
    if (node >= N) return;
    const ushort* hp = H + (size_t)node * HC + lane * VPL;
    float esum = 0.f, dsum = 0.f;
#pragma unroll
    for (int j = 0; j < VPL; j++) {
        float h = bf2f(hp[j]);
        int ch = lane * VPL + j;
        esum += h * asrc[ch];
        dsum += h * adst[ch];
    }
#pragma unroll
    for (int off = 1; off < 16; off <<= 1) {
        esum += __shfl_xor(esum, off, 64);
        dsum += __shfl_xor(dsum, off, 64);
    }
    if ((lane & 15) == 0) {
        int hh = lane >> 4;
        es[node * 4 + hh] = esum;
        ed[node * 4 + hh] = dsum;
    }
}

// ---------- fused CSR-gather softmax-aggregate + bias + (ELU) + LayerNorm ----------
// v3: 16-lane groups, ONE NODE PER GROUP (4 nodes/wave). Lane owns HC/16
// channels; head = ln>>2 for both HC=256 and HC=128. 8 independent edge
// chains per wave (4 groups x unroll 2). Reductions within 16-lane group.
template <int HC>  // 256 or 128
__global__ __launch_bounds__(256) void agg_gather(
    const ushort* __restrict__ H, const float* __restrict__ es, const float* __restrict__ ed,
    const int* __restrict__ rowptr, const int* __restrict__ srcs,
    const float* __restrict__ bias, const float* __restrict__ gamma,
    const float* __restrict__ beta, ushort* __restrict__ XoutB, float* __restrict__ XoutF,
    int N, int applyElu) {
    constexpr int EPL = HC / 16;  // channels per lane (16 or 8)
    int ln = threadIdx.x & 15;
    int node = (blockIdx.x * blockDim.x + threadIdx.x) >> 4;
    if (node >= N) return;
    int base = rowptr[node];
    int deg = rowptr[node + 1] - base;
    float4 ed4 = *(const float4*)&ed[node * 4];

    // pass A: softmax denominator per head (16-lane edge-parallel)
    float4 sm = make_float4(0.f, 0.f, 0.f, 0.f);
    for (int i = ln; i < deg; i += 16) {
        int s = srcs[base + i];
        float4 e4 = *(const float4*)&es[(size_t)s * 4];
        sm.x += __expf(lrelu(e4.x + ed4.x));
        sm.y += __expf(lrelu(e4.y + ed4.y));
        sm.z += __expf(lrelu(e4.z + ed4.z));
        sm.w += __expf(lrelu(e4.w + ed4.w));
    }
#pragma unroll
    for (int off = 1; off < 16; off <<= 1) {
        sm.x += __shfl_xor(sm.x, off, 64);
        sm.y += __shfl_xor(sm.y, off, 64);
        sm.z += __shfl_xor(sm.z, off, 64);
        sm.w += __shfl_xor(sm.w, off, 64);
    }

    int hh = ln >> 2;  // head: HC=256 -> ch=ln*16, ch/64=ln>>2; HC=128 -> ch=ln*8, ch/32=ln>>2
    float rd_h = 1.f / ((hh == 0) ? sm.x : (hh == 1) ? sm.y : (hh == 2) ? sm.z : sm.w);
    float edh = (hh == 0) ? ed4.x : (hh == 1) ? ed4.y : (hh == 2) ? ed4.z : ed4.w;

    // pass B: 2 edges in flight per group
    float acc[EPL];
#pragma unroll
    for (int j = 0; j < EPL; j++) acc[j] = 0.f;
    const ushort* Hl = H + ln * EPL;

    int i = 0;
    for (; i + 2 <= deg; i += 2) {
        int s0 = srcs[base + i];
        int s1 = srcs[base + i + 1];
        float e0 = es[(size_t)s0 * 4 + hh];
        float e1 = es[(size_t)s1 * 4 + hh];
        const ushort* hp0 = Hl + (size_t)s0 * HC;
        const ushort* hp1 = Hl + (size_t)s1 * HC;
        float a0 = __expf(lrelu(e0 + edh)) * rd_h;
        float a1 = __expf(lrelu(e1 + edh)) * rd_h;
        if constexpr (EPL == 16) {
            u16x8 h0a = *(const u16x8*)hp0;
            u16x8 h0b = *(const u16x8*)(hp0 + 8);
            u16x8 h1a = *(const u16x8*)hp1;
            u16x8 h1b = *(const u16x8*)(hp1 + 8);
#pragma unroll
            for (int j = 0; j < 8; j++) {
                acc[j] += a0 * bf2f(h0a[j]) + a1 * bf2f(h1a[j]);
                acc[j + 8] += a0 * bf2f(h0b[j]) + a1 * bf2f(h1b[j]);
            }
        } else {
            u16x8 h0 = *(const u16x8*)hp0;
            u16x8 h1 = *(const u16x8*)hp1;
#pragma unroll
            for (int j = 0; j < 8; j++)
                acc[j] += a0 * bf2f(h0[j]) + a1 * bf2f(h1[j]);
        }
    }
    if (i < deg) {
        int s = srcs[base + i];
        float a = __expf(lrelu(es[(size_t)s * 4 + hh] + edh)) * rd_h;
        const ushort* hp = Hl + (size_t)s * HC;
        if constexpr (EPL == 16) {
            u16x8 ha = *(const u16x8*)hp;
            u16x8 hb = *(const u16x8*)(hp + 8);
#pragma unroll
            for (int j = 0; j < 8; j++) {
                acc[j] += a * bf2f(ha[j]);
                acc[j + 8] += a * bf2f(hb[j]);
            }
        } else {
            u16x8 hv = *(const u16x8*)hp;
#pragma unroll
            for (int j = 0; j < 8; j++) acc[j] += a * bf2f(hv[j]);
        }
    }

    // epilogue: bias, optional ELU, LayerNorm over the 16-lane group
    float v[EPL];
    float s1 = 0.f, s2 = 0.f;
#pragma unroll
    for (int j = 0; j < EPL; j++) {
        int ch = ln * EPL + j;
        float t = acc[j] + bias[ch];
        if (applyElu) t = (t > 0.f) ? t : (__expf(t) - 1.f);
        v[j] = t;
        s1 += t;
        s2 += t * t;
    }
#pragma unroll
    for (int off = 1; off < 16; off <<= 1) {
        s1 += __shfl_xor(s1, off, 64);
        s2 += __shfl_xor(s2, off, 64);
    }
    float mu = s1 / (float)HC;
    float var = s2 / (float)HC - mu * mu;
    float rs = rsqrtf(var + 1e-5f);
#pragma unroll
    for (int j = 0; j < EPL; j++) {
        int ch = ln * EPL + j;
        float o = gamma[ch] * (v[j] - mu) * rs + beta[ch];
        if (XoutF) XoutF[(size_t)node * HC + ch] = o;
        else XoutB[(size_t)node * HC + ch] = f2bf(o);
    }
}

// ---------- graph pooling: sorted-run flush ----------
__global__ __launch_bounds__(128) void gsum_kernel(const float* __restrict__ node_emb,
                                                   const int* __restrict__ batch,
                                                   float* __restrict__ gsum,
                                                   int* __restrict__ gcnt, int N) {
    int start = blockIdx.x * 256;
    if (start >= N) return;
    int end = min(start + 256, N);
    int ch = threadIdx.x;
    float acc = 0.f;
    int runlen = 0;
    int curg = batch[start];
    for (int n = start; n < end; n++) {
        int g = batch[n];
        if (g != curg) {
            atomicAdd(&gsum[curg * 128 + ch], acc);
            if (ch == 0) atomicAdd(&gcnt[curg], runlen);
            acc = 0.f; runlen = 0; curg = g;
        }
        acc += node_emb[(size_t)n * 128 + ch];
        runlen++;
    }
    atomicAdd(&gsum[curg * 128 + ch], acc);
    if (ch == 0) atomicAdd(&gcnt[curg], runlen);
}

__global__ void gfinal_kernel(const float* __restrict__ gsum, const int* __restrict__ gcnt,
                              float* __restrict__ out, int Gn) {
    int i = blockIdx.x * blockDim.x + threadIdx.x;
    if (i >= Gn * 128) return;
    int g = i >> 7;
    out[i] = gsum[i] / fmaxf((float)gcnt[g], 1.f);
}

// ---------- launch ----------
extern "C" void kernel_launch(void* const* d_in, const int* in_sizes, int n_in, void* d_out,
                              int out_size, void* d_ws, size_t ws_size, hipStream_t stream) {
    const float* x = (const float*)d_in[0];
    const int* ei = (const int*)d_in[1];
    const int* batch = (const int*)d_in[2];
    const float* W1 = (const float*)d_in[3];
    const float* as1 = (const float*)d_in[4];
    const float* ad1 = (const float*)d_in[5];
    const float* b1 = (const float*)d_in[6];
    const float* g1 = (const float*)d_in[7];
    const float* be1 = (const float*)d_in[8];
    const float* W2 = (const float*)d_in[9];
    const float* as2 = (const float*)d_in[10];
    const float* ad2 = (const float*)d_in[11];
    const float* b2 = (const float*)d_in[12];
    const float* g2 = (const float*)d_in[13];
    const float* be2 = (const float*)d_in[14];
    const float* W3 = (const float*)d_in[15];
    const float* as3 = (const float*)d_in[16];
    const float* ad3 = (const float*)d_in[17];
    const float* b3 = (const float*)d_in[18];
    const float* g3 = (const float*)d_in[19];
    const float* be3 = (const float*)d_in[20];

    int N = in_sizes[2];
    int E = in_sizes[1] / 2;
    int Etot = E + N;

    char* w = (char*)d_ws;
    size_t off = 0;
    auto alloc = [&](size_t bytes) -> void* {
        void* p = w + off;
        off += (bytes + 255) & ~(size_t)255;
        return p;
    };
    int* cnt = (int*)alloc((size_t)N * 4);       // | zero region
    int* pos = (int*)alloc((size_t)N * 4);       // |
    float* gsum = (float*)alloc(64 * 128 * 4);   // |
    int* gcnt = (int*)alloc(64 * 4);             // |
    size_t zbytes = off;
    int* scantmp = (int*)alloc((size_t)N * 4);
    int* btot = (int*)alloc(1024 * 4);
    int* rowptr = (int*)alloc((size_t)(N + 1) * 4);
    int* srcs = (int*)alloc((size_t)Etot * 4);
    float* es = (float*)alloc((size_t)N * 16);
    float* ed = (float*)alloc((size_t)N * 16);
    ushort* Hb = (ushort*)alloc((size_t)N * 256 * 2);  // bf16 H
    ushort* Xb = (ushort*)alloc((size_t)N * 256 * 2);  // bf16 X (inter-layer)
    ushort* wt1 = (ushort*)alloc((size_t)768 * 256 * 2);  // W^T bf16 [N][K]
    ushort* wt2 = (ushort*)alloc((size_t)256 * 256 * 2);
    ushort* wt3 = (ushort*)alloc((size_t)256 * 128 * 2);

    hipMemsetAsync(d_ws, 0, zbytes, stream);

    const int* srcrow = ei;
    const int* dstrow = ei + E;

    // weight pre-transpose (tiny)
    wconv_kernel<<<dim3(768 / 32, 256 / 32), 256, 0, stream>>>(W1, wt1, 768, 256);
    wconv_kernel<<<dim3(256 / 32, 256 / 32), 256, 0, stream>>>(W2, wt2, 256, 256);
    wconv_kernel<<<dim3(256 / 32, 128 / 32), 256, 0, stream>>>(W3, wt3, 256, 128);

    int eb = (Etot + 255) / 256;
    int nb = (N + 255) / 256;
    hist_kernel<<<eb, 256, 0, stream>>>(dstrow, cnt, Etot, E);
    scan1_kernel<<<nb, 256, 0, stream>>>(cnt, scantmp, btot, N);
    scan2_kernel<<<1, 1024, 0, stream>>>(btot, nb);
    scan3_kernel<<<nb, 256, 0, stream>>>(scantmp, btot, rowptr, N);
    fill_kernel<<<eb, 256, 0, stream>>>(srcrow, dstrow, rowptr, pos, srcs, Etot, E);

    int mT = (N + 127) / 128;
    int nodeWaveBlocks = (N + 3) / 4;
    int nodeGroupBlocks = (N + 15) / 16;

    float* out_node = (float*)d_out;                     // [N,128] f32
    float* out_graph = (float*)d_out + (size_t)N * 128;  // [64,128] f32

    // ---- layer 1: 768 -> 256 ----
    gemm_mfma2<float><<<dim3(2, mT), 256, 0, stream>>>(x, wt1, Hb, N, 768, 256);
    attn_wave<4><<<nodeWaveBlocks, 256, 0, stream>>>(Hb, as1, ad1, es, ed, N);
    agg_gather<256><<<nodeGroupBlocks, 256, 0, stream>>>(Hb, es, ed, rowptr, srcs, b1, g1, be1,
                                                         Xb, nullptr, N, 1);
    // ---- layer 2: 256 -> 256 ----
    gemm_mfma2<ushort><<<dim3(2, mT), 256, 0, stream>>>(Xb, wt2, Hb, N, 256, 256);
    attn_wave<4><<<nodeWaveBlocks, 256, 0, stream>>>(Hb, as2, ad2, es, ed, N);
    agg_gather<256><<<nodeGroupBlocks, 256, 0, stream>>>(Hb, es, ed, rowptr, srcs, b2, g2, be2,
                                                         Xb, nullptr, N, 1);
    // ---- layer 3: 256 -> 128 (no ELU; node_emb -> d_out f32) ----
    gemm_mfma2<ushort><<<dim3(1, mT), 256, 0, stream>>>(Xb, wt3, Hb, N, 256, 128);
    attn_wave<2><<<nodeWaveBlocks, 256, 0, stream>>>(Hb, as3, ad3, es, ed, N);
    agg_gather<128><<<nodeGroupBlocks, 256, 0, stream>>>(Hb, es, ed, rowptr, srcs, b3, g3, be3,
                                                         nullptr, out_node, N, 0);
    // ---- graph pooling ----
    gsum_kernel<<<(N + 255) / 256, 128, 0, stream>>>(out_node, batch, gsum, gcnt, N);
    gfinal_kernel<<<(64 * 128 + 255) / 256, 256, 0, stream>>>(gsum, gcnt, out_graph, 64);
}

// Round 7
// 772.251 us; speedup vs baseline: 1.0528x; 1.0528x over previous
//
#include <hip/hip_runtime.h>
#include <math.h>

// ---------- helpers ----------
__device__ __forceinline__ float lrelu(float v) { return v > 0.f ? v : 0.2f * v; }
__device__ __forceinline__ float bf2f(ushort u) {
    return __uint_as_float(((unsigned int)u) << 16);
}
__device__ __forceinline__ ushort f2bf(float f) {
    unsigned int x = __float_as_uint(f);
    return (ushort)((x + 0x7fffu + ((x >> 16) & 1u)) >> 16);
}
__device__ __forceinline__ float wave_allred_sum(float v) {
#pragma unroll
    for (int off = 1; off < 64; off <<= 1) v += __shfl_xor(v, off, 64);
    return v;
}

typedef short bf16x8 __attribute__((ext_vector_type(8)));
typedef float f32x4 __attribute__((ext_vector_type(4)));

typedef const __attribute__((address_space(1))) void* gas_ptr;
typedef __attribute__((address_space(3))) void* las_ptr;
__device__ __forceinline__ void gload_lds16(const void* g, void* l) {
    __builtin_amdgcn_global_load_lds((gas_ptr)g, (las_ptr)l, 16, 0, 0);
}

// ---------- CSR build ----------
__global__ void hist_kernel(const int* __restrict__ dstrow, int* __restrict__ cnt,
                            int Etot, int E) {
    int i = blockIdx.x * blockDim.x + threadIdx.x;
    if (i >= Etot) return;
    int d = (i < E) ? dstrow[i] : (i - E);
    atomicAdd(&cnt[d], 1);
}

__global__ __launch_bounds__(256) void scan1_kernel(const int* __restrict__ cnt,
                                                    int* __restrict__ out,
                                                    int* __restrict__ btot, int n) {
    __shared__ int s[256];
    int i = blockIdx.x * 256 + threadIdx.x;
    int v = (i < n) ? cnt[i] : 0;
    s[threadIdx.x] = v;
    __syncthreads();
    for (int off = 1; off < 256; off <<= 1) {
        int t = (threadIdx.x >= off) ? s[threadIdx.x - off] : 0;
        __syncthreads();
        s[threadIdx.x] += t;
        __syncthreads();
    }
    if (i < n) out[i] = s[threadIdx.x];
    if (threadIdx.x == 255) btot[blockIdx.x] = s[255];
}
__global__ __launch_bounds__(1024) void scan2_kernel(int* __restrict__ btot, int nb) {
    __shared__ int s[1024];
    int tid = threadIdx.x;
    int v = (tid < nb) ? btot[tid] : 0;
    s[tid] = v;
    __syncthreads();
    for (int off = 1; off < 1024; off <<= 1) {
        int t = (tid >= off) ? s[tid - off] : 0;
        __syncthreads();
        s[tid] += t;
        __syncthreads();
    }
    if (tid < nb) btot[tid] = s[tid] - v;  // exclusive
}
__global__ void scan3_kernel(const int* __restrict__ scanned, const int* __restrict__ btot,
                             int* __restrict__ rowptr, int n) {
    int i = blockIdx.x * 256 + threadIdx.x;
    if (i < n) rowptr[i + 1] = scanned[i] + btot[i >> 8];
    if (i == 0) rowptr[0] = 0;
}

__global__ void fill_kernel(const int* __restrict__ srcrow, const int* __restrict__ dstrow,
                            const int* __restrict__ rowptr, int* __restrict__ pos,
                            int* __restrict__ srcs, int Etot, int E) {
    int i = blockIdx.x * blockDim.x + threadIdx.x;
    if (i >= Etot) return;
    int d = (i < E) ? dstrow[i] : (i - E);
    int s = (i < E) ? srcrow[i] : (i - E);
    int p = atomicAdd(&pos[d], 1);
    srcs[rowptr[d] + p] = s;
}

// ---------- weight pre-transpose: W[K][N] f32 -> Wt[N][K] bf16 ----------
__global__ __launch_bounds__(256) void wconv_kernel(const float* __restrict__ W,
                                                    ushort* __restrict__ Wt, int K, int N) {
    __shared__ float t[32][33];
    int k0 = blockIdx.x * 32, n0 = blockIdx.y * 32;
    int tx = threadIdx.x & 31, ty = threadIdx.x >> 5;  // ty: 0..7
#pragma unroll
    for (int i = 0; i < 32; i += 8)
        t[ty + i][tx] = W[(size_t)(k0 + ty + i) * N + n0 + tx];
    __syncthreads();
#pragma unroll
    for (int i = 0; i < 32; i += 8)
        Wt[(size_t)(n0 + ty + i) * K + k0 + tx] = f2bf(t[tx][ty + i]);
}

// ---------- MFMA GEMM (round-1 verified): C[M,N](bf16) = A @ Wt[N,K](bf16) ----------
template <typename TA>
__global__ __launch_bounds__(256) void gemm_mfma2(const TA* __restrict__ A,
                                                  const ushort* __restrict__ Wt,
                                                  ushort* __restrict__ C,
                                                  int M, int K, int N) {
    constexpr bool F32A = (sizeof(TA) == 4);
    constexpr int ASZ = F32A ? 16384 : 8192;  // per-buffer A bytes
    __shared__ __align__(16) unsigned char smem[2 * ASZ + 16384];

    int tid = threadIdx.x;
    int wv = tid >> 6, lane = tid & 63;
    int quad = lane >> 4, mrow = lane & 15;

    // bijective XCD-chunk swizzle (m204)
    int nwg = gridDim.x * gridDim.y;
    int id = blockIdx.y * gridDim.x + blockIdx.x;
    int q8 = nwg >> 3, r8 = nwg & 7;
    int xcd = id & 7, loc = id >> 3;
    int wgid = (xcd < r8 ? xcd * (q8 + 1) : r8 * (q8 + 1) + (xcd - r8) * q8) + loc;
    int n0 = (wgid % gridDim.x) * 128;
    int m0 = (wgid / gridDim.x) * 128;

    f32x4 acc[2][8] = {};

    auto stageA = [&](int kt, int buf) {
        unsigned char* lb = smem + buf * ASZ;
        if constexpr (F32A) {
#pragma unroll
            for (int q = 0; q < 4; q++) {
                int row = q * 32 + (tid >> 3);
                int gch = (tid & 7) ^ (row & 7);
                int rc = min(m0 + row, M - 1);
                gload_lds16((const float*)A + (size_t)rc * K + kt + gch * 4,
                            lb + q * 4096 + tid * 16);
            }
        } else {
#pragma unroll
            for (int q = 0; q < 2; q++) {
                int row = q * 64 + (tid >> 2);
                int gch = (tid & 3) ^ ((row & 3) ^ ((row >> 2) & 1));
                int rc = min(m0 + row, M - 1);
                gload_lds16((const ushort*)A + (size_t)rc * K + kt + gch * 8,
                            lb + q * 4096 + tid * 16);
            }
        }
    };
    auto stageB = [&](int kt, int buf) {
        unsigned char* lb = smem + 2 * ASZ + buf * 8192;
#pragma unroll
        for (int q = 0; q < 2; q++) {
            int row = q * 64 + (tid >> 2);
            int gch = (tid & 3) ^ ((row & 3) ^ ((row >> 2) & 1));
            gload_lds16(Wt + (size_t)(n0 + row) * K + kt + gch * 8,
                        lb + q * 4096 + tid * 16);
        }
    };

    int nsteps = K >> 5;
    stageA(0, 0);
    stageB(0, 0);
    __syncthreads();

    for (int s = 0; s < nsteps; s++) {
        int kt = s << 5;
        if (s + 1 < nsteps) {
            stageA(kt + 32, (s + 1) & 1);
            stageB(kt + 32, (s + 1) & 1);
        }
        const unsigned char* la = smem + (s & 1) * ASZ;
        const unsigned char* lbB = smem + 2 * ASZ + (s & 1) * 8192;

        bf16x8 afrag[2], bfrag[8];
#pragma unroll
        for (int r = 0; r < 2; r++) {
            int row = wv * 32 + r * 16 + mrow;
            if constexpr (F32A) {
                int f = row & 7;
                float4 x0 = *(const float4*)(la + row * 128 + ((quad * 2 + 0) ^ f) * 16);
                float4 x1 = *(const float4*)(la + row * 128 + ((quad * 2 + 1) ^ f) * 16);
                union { bf16x8 v; ushort u[8]; } t;
                t.u[0] = f2bf(x0.x); t.u[1] = f2bf(x0.y);
                t.u[2] = f2bf(x0.z); t.u[3] = f2bf(x0.w);
                t.u[4] = f2bf(x1.x); t.u[5] = f2bf(x1.y);
                t.u[6] = f2bf(x1.z); t.u[7] = f2bf(x1.w);
                afrag[r] = t.v;
            } else {
                int f = (row & 3) ^ ((row >> 2) & 1);
                afrag[r] = *(const bf16x8*)(la + row * 64 + (quad ^ f) * 16);
            }
        }
#pragma unroll
        for (int c = 0; c < 8; c++) {
            int row = c * 16 + mrow;
            int f = (row & 3) ^ ((row >> 2) & 1);
            bfrag[c] = *(const bf16x8*)(lbB + row * 64 + (quad ^ f) * 16);
        }
#pragma unroll
        for (int r = 0; r < 2; r++)
#pragma unroll
            for (int c = 0; c < 8; c++)
                acc[r][c] = __builtin_amdgcn_mfma_f32_16x16x32_bf16(afrag[r], bfrag[c],
                                                                    acc[r][c], 0, 0, 0);
        __syncthreads();
    }

    int col = lane & 15;
#pragma unroll
    for (int r = 0; r < 2; r++) {
#pragma unroll
        for (int c = 0; c < 8; c++) {
#pragma unroll
            for (int reg = 0; reg < 4; reg++) {
                int gm = m0 + wv * 32 + r * 16 + quad * 4 + reg;
                int gn = n0 + c * 16 + col;
                if (gm < M) C[(size_t)gm * N + gn] = f2bf(acc[r][c][reg]);
            }
        }
    }
}

// ---------- attention logits: one wave per node, bf16 H ----------
template <int VPL>
__global__ __launch_bounds__(256) void attn_wave(const ushort* __restrict__ H,
                                                 const float* __restrict__ asrc,
                                                 const float* __restrict__ adst,
                                                 float* __restrict__ es, float* __restrict__ ed,
                                                 int N) {
    constexpr int HC = VPL * 64;
    int lane = threadIdx.x & 63;
    int node = (blockIdx.x * blockDim.x + threadIdx.x) >> 6;
    if (node >= N) return;
    const ushort* hp = H + (size_t)node * HC + lane * VPL;
    float esum = 0.f, dsum = 0.f;
#pragma unroll
    for (int j = 0; j < VPL; j++) {
        float h = bf2f(hp[j]);
        int ch = lane * VPL + j;
        esum += h * asrc[ch];
        dsum += h * adst[ch];
    }
#pragma unroll
    for (int off = 1; off < 16; off <<= 1) {
        esum += __shfl_xor(esum, off, 64);
        dsum += __shfl_xor(dsum, off, 64);
    }
    if ((lane & 15) == 0) {
        int hh = lane >> 4;
        es[node * 4 + hh] = esum;
        ed[node * 4 + hh] = dsum;
    }
}

// ---------- fused CSR-gather softmax-aggregate + bias + (ELU) + LayerNorm ----------
// v5 = round-1 structure (one 64-lane wave per node) + per-edge numerator
// cache: pass A computes pv = exp(lrelu(es[src]+ed)) ONCE per edge and stores
// it to pbuf; pass B reads alpha = pbuf[...]*rd sequentially — the random es
// gather and the exp/lrelu disappear from the weighted-gather inner loop.
template <int VPL>
__global__ __launch_bounds__(256) void agg_gather(
    const ushort* __restrict__ H, const float* __restrict__ es, const float* __restrict__ ed,
    const int* __restrict__ rowptr, const int* __restrict__ srcs, float* pbuf,
    const float* __restrict__ bias, const float* __restrict__ gamma,
    const float* __restrict__ beta, ushort* __restrict__ XoutB, float* __restrict__ XoutF,
    int N, int applyElu) {
    constexpr int HC = VPL * 64;
    int lane = threadIdx.x & 63;
    int node = (blockIdx.x * blockDim.x + threadIdx.x) >> 6;
    if (node >= N) return;
    int base = rowptr[node];
    int deg = rowptr[node + 1] - base;
    float4 ed4 = *(const float4*)&ed[node * 4];

    // pass A: per-edge numerators -> pbuf, accumulate softmax denominator
    float4 sm = make_float4(0.f, 0.f, 0.f, 0.f);
    for (int i = lane; i < deg; i += 64) {
        int s = srcs[base + i];
        float4 e4 = *(const float4*)&es[(size_t)s * 4];
        float4 pv;
        pv.x = __expf(lrelu(e4.x + ed4.x));
        pv.y = __expf(lrelu(e4.y + ed4.y));
        pv.z = __expf(lrelu(e4.z + ed4.z));
        pv.w = __expf(lrelu(e4.w + ed4.w));
        *(float4*)&pbuf[(size_t)(base + i) * 4] = pv;
        sm.x += pv.x; sm.y += pv.y; sm.z += pv.z; sm.w += pv.w;
    }
    sm.x = wave_allred_sum(sm.x); sm.y = wave_allred_sum(sm.y);
    sm.z = wave_allred_sum(sm.z); sm.w = wave_allred_sum(sm.w);

    int hh = lane >> 4;
    float rd_h = 1.f / ((hh == 0) ? sm.x : (hh == 1) ? sm.y : (hh == 2) ? sm.z : sm.w);

    // pass B: weighted gather of bf16 rows; alpha from sequential pbuf reads
    float acc[VPL];
#pragma unroll
    for (int j = 0; j < VPL; j++) acc[j] = 0.f;
    const ushort* Hl = H + lane * VPL;
    const float* pb = pbuf + (size_t)base * 4 + hh;

    int i = 0;
    for (; i + 2 <= deg; i += 2) {
        int s0 = srcs[base + i];
        int s1 = srcs[base + i + 1];
        float a0 = pb[(size_t)i * 4] * rd_h;
        float a1 = pb[(size_t)(i + 1) * 4] * rd_h;
        const ushort* hp0 = Hl + (size_t)s0 * HC;
        const ushort* hp1 = Hl + (size_t)s1 * HC;
        if constexpr (VPL == 4) {
            ushort4 h0 = *(const ushort4*)hp0;
            ushort4 h1 = *(const ushort4*)hp1;
            acc[0] += a0 * bf2f(h0.x) + a1 * bf2f(h1.x);
            acc[1] += a0 * bf2f(h0.y) + a1 * bf2f(h1.y);
            acc[2] += a0 * bf2f(h0.z) + a1 * bf2f(h1.z);
            acc[3] += a0 * bf2f(h0.w) + a1 * bf2f(h1.w);
        } else {
            ushort2 h0 = *(const ushort2*)hp0;
            ushort2 h1 = *(const ushort2*)hp1;
            acc[0] += a0 * bf2f(h0.x) + a1 * bf2f(h1.x);
            acc[1] += a0 * bf2f(h0.y) + a1 * bf2f(h1.y);
        }
    }
    for (; i < deg; i++) {
        int s = srcs[base + i];
        float a = pb[(size_t)i * 4] * rd_h;
        const ushort* hp = Hl + (size_t)s * HC;
        if constexpr (VPL == 4) {
            ushort4 hv = *(const ushort4*)hp;
            acc[0] += a * bf2f(hv.x); acc[1] += a * bf2f(hv.y);
            acc[2] += a * bf2f(hv.z); acc[3] += a * bf2f(hv.w);
        } else {
            ushort2 hv = *(const ushort2*)hp;
            acc[0] += a * bf2f(hv.x); acc[1] += a * bf2f(hv.y);
        }
    }

    // epilogue: bias, optional ELU, LayerNorm
    float v[VPL];
    float s1 = 0.f, s2 = 0.f;
#pragma unroll
    for (int j = 0; j < VPL; j++) {
        int ch = lane * VPL + j;
        float t = acc[j] + bias[ch];
        if (applyElu) t = (t > 0.f) ? t : (__expf(t) - 1.f);
        v[j] = t;
        s1 += t;
        s2 += t * t;
    }
    s1 = wave_allred_sum(s1);
    s2 = wave_allred_sum(s2);
    float mu = s1 / (float)HC;
    float var = s2 / (float)HC - mu * mu;
    float rs = rsqrtf(var + 1e-5f);
#pragma unroll
    for (int j = 0; j < VPL; j++) {
        int ch = lane * VPL + j;
        float o = gamma[ch] * (v[j] - mu) * rs + beta[ch];
        if (XoutF) XoutF[(size_t)node * HC + ch] = o;
        else XoutB[(size_t)node * HC + ch] = f2bf(o);
    }
}

// ---------- graph pooling: sorted-run flush ----------
__global__ __launch_bounds__(128) void gsum_kernel(const float* __restrict__ node_emb,
                                                   const int* __restrict__ batch,
                                                   float* __restrict__ gsum,
                                                   int* __restrict__ gcnt, int N) {
    int start = blockIdx.x * 256;
    if (start >= N) return;
    int end = min(start + 256, N);
    int ch = threadIdx.x;
    float acc = 0.f;
    int runlen = 0;
    int curg = batch[start];
    for (int n = start; n < end; n++) {
        int g = batch[n];
        if (g != curg) {
            atomicAdd(&gsum[curg * 128 + ch], acc);
            if (ch == 0) atomicAdd(&gcnt[curg], runlen);
            acc = 0.f; runlen = 0; curg = g;
        }
        acc += node_emb[(size_t)n * 128 + ch];
        runlen++;
    }
    atomicAdd(&gsum[curg * 128 + ch], acc);
    if (ch == 0) atomicAdd(&gcnt[curg], runlen);
}

__global__ void gfinal_kernel(const float* __restrict__ gsum, const int* __restrict__ gcnt,
                              float* __restrict__ out, int Gn) {
    int i = blockIdx.x * blockDim.x + threadIdx.x;
    if (i >= Gn * 128) return;
    int g = i >> 7;
    out[i] = gsum[i] / fmaxf((float)gcnt[g], 1.f);
}

// ---------- launch ----------
extern "C" void kernel_launch(void* const* d_in, const int* in_sizes, int n_in, void* d_out,
                              int out_size, void* d_ws, size_t ws_size, hipStream_t stream) {
    const float* x = (const float*)d_in[0];
    const int* ei = (const int*)d_in[1];
    const int* batch = (const int*)d_in[2];
    const float* W1 = (const float*)d_in[3];
    const float* as1 = (const float*)d_in[4];
    const float* ad1 = (const float*)d_in[5];
    const float* b1 = (const float*)d_in[6];
    const float* g1 = (const float*)d_in[7];
    const float* be1 = (const float*)d_in[8];
    const float* W2 = (const float*)d_in[9];
    const float* as2 = (const float*)d_in[10];
    const float* ad2 = (const float*)d_in[11];
    const float* b2 = (const float*)d_in[12];
    const float* g2 = (const float*)d_in[13];
    const float* be2 = (const float*)d_in[14];
    const float* W3 = (const float*)d_in[15];
    const float* as3 = (const float*)d_in[16];
    const float* ad3 = (const float*)d_in[17];
    const float* b3 = (const float*)d_in[18];
    const float* g3 = (const float*)d_in[19];
    const float* be3 = (const float*)d_in[20];

    int N = in_sizes[2];
    int E = in_sizes[1] / 2;
    int Etot = E + N;

    char* w = (char*)d_ws;
    size_t off = 0;
    auto alloc = [&](size_t bytes) -> void* {
        void* p = w + off;
        off += (bytes + 255) & ~(size_t)255;
        return p;
    };
    int* cnt = (int*)alloc((size_t)N * 4);       // | zero region
    int* pos = (int*)alloc((size_t)N * 4);       // |
    float* gsum = (float*)alloc(64 * 128 * 4);   // |
    int* gcnt = (int*)alloc(64 * 4);             // |
    size_t zbytes = off;
    int* scantmp = (int*)alloc((size_t)N * 4);
    int* btot = (int*)alloc(1024 * 4);
    int* rowptr = (int*)alloc((size_t)(N + 1) * 4);
    int* srcs = (int*)alloc((size_t)Etot * 4);
    float* es = (float*)alloc((size_t)N * 16);
    float* ed = (float*)alloc((size_t)N * 16);
    float* pbuf = (float*)alloc((size_t)Etot * 16);    // per-edge numerator cache
    ushort* Hb = (ushort*)alloc((size_t)N * 256 * 2);  // bf16 H
    ushort* Xb = (ushort*)alloc((size_t)N * 256 * 2);  // bf16 X (inter-layer)
    ushort* wt1 = (ushort*)alloc((size_t)768 * 256 * 2);  // W^T bf16 [N][K]
    ushort* wt2 = (ushort*)alloc((size_t)256 * 256 * 2);
    ushort* wt3 = (ushort*)alloc((size_t)256 * 128 * 2);

    hipMemsetAsync(d_ws, 0, zbytes, stream);

    const int* srcrow = ei;
    const int* dstrow = ei + E;

    // weight pre-transpose (tiny)
    wconv_kernel<<<dim3(768 / 32, 256 / 32), 256, 0, stream>>>(W1, wt1, 768, 256);
    wconv_kernel<<<dim3(256 / 32, 256 / 32), 256, 0, stream>>>(W2, wt2, 256, 256);
    wconv_kernel<<<dim3(256 / 32, 128 / 32), 256, 0, stream>>>(W3, wt3, 256, 128);

    int eb = (Etot + 255) / 256;
    int nb = (N + 255) / 256;
    hist_kernel<<<eb, 256, 0, stream>>>(dstrow, cnt, Etot, E);
    scan1_kernel<<<nb, 256, 0, stream>>>(cnt, scantmp, btot, N);
    scan2_kernel<<<1, 1024, 0, stream>>>(btot, nb);
    scan3_kernel<<<nb, 256, 0, stream>>>(scantmp, btot, rowptr, N);
    fill_kernel<<<eb, 256, 0, stream>>>(srcrow, dstrow, rowptr, pos, srcs, Etot, E);

    int mT = (N + 127) / 128;
    int nodeWaveBlocks = (N + 3) / 4;

    float* out_node = (float*)d_out;                     // [N,128] f32
    float* out_graph = (float*)d_out + (size_t)N * 128;  // [64,128] f32

    // ---- layer 1: 768 -> 256 ----
    gemm_mfma2<float><<<dim3(2, mT), 256, 0, stream>>>(x, wt1, Hb, N, 768, 256);
    attn_wave<4><<<nodeWaveBlocks, 256, 0, stream>>>(Hb, as1, ad1, es, ed, N);
    agg_gather<4><<<nodeWaveBlocks, 256, 0, stream>>>(Hb, es, ed, rowptr, srcs, pbuf,
                                                      b1, g1, be1, Xb, nullptr, N, 1);
    // ---- layer 2: 256 -> 256 ----
    gemm_mfma2<ushort><<<dim3(2, mT), 256, 0, stream>>>(Xb, wt2, Hb, N, 256, 256);
    attn_wave<4><<<nodeWaveBlocks, 256, 0, stream>>>(Hb, as2, ad2, es, ed, N);
    agg_gather<4><<<nodeWaveBlocks, 256, 0, stream>>>(Hb, es, ed, rowptr, srcs, pbuf,
                                                      b2, g2, be2, Xb, nullptr, N, 1);
    // ---- layer 3: 256 -> 128 (no ELU; node_emb -> d_out f32) ----
    gemm_mfma2<ushort><<<dim3(1, mT), 256, 0, stream>>>(Xb, wt3, Hb, N, 256, 128);
    attn_wave<2><<<nodeWaveBlocks, 256, 0, stream>>>(Hb, as3, ad3, es, ed, N);
    agg_gather<2><<<nodeWaveBlocks, 256, 0, stream>>>(Hb, es, ed, rowptr, srcs, pbuf,
                                                      b3, g3, be3, nullptr, out_node, N, 0);
    // ---- graph pooling ----
    gsum_kernel<<<(N + 255) / 256, 128, 0, stream>>>(out_node, batch, gsum, gcnt, N);
    gfinal_kernel<<<(64 * 128 + 255) / 256, 256, 0, stream>>>(gsum, gcnt, out_graph, 64);
}

// Round 8
// 767.599 us; speedup vs baseline: 1.0592x; 1.0061x over previous
//
#include <hip/hip_runtime.h>
#include <math.h>

// ---------- helpers ----------
__device__ __forceinline__ float lrelu(float v) { return v > 0.f ? v : 0.2f * v; }
__device__ __forceinline__ float bf2f(ushort u) {
    return __uint_as_float(((unsigned int)u) << 16);
}
__device__ __forceinline__ ushort f2bf(float f) {
    unsigned int x = __float_as_uint(f);
    return (ushort)((x + 0x7fffu + ((x >> 16) & 1u)) >> 16);
}
__device__ __forceinline__ float wave_allred_sum(float v) {
#pragma unroll
    for (int off = 1; off < 64; off <<= 1) v += __shfl_xor(v, off, 64);
    return v;
}

typedef short bf16x8 __attribute__((ext_vector_type(8)));
typedef float f32x4 __attribute__((ext_vector_type(4)));

typedef const __attribute__((address_space(1))) void* gas_ptr;
typedef __attribute__((address_space(3))) void* las_ptr;
__device__ __forceinline__ void gload_lds16(const void* g, void* l) {
    __builtin_amdgcn_global_load_lds((gas_ptr)g, (las_ptr)l, 16, 0, 0);
}

// ---------- CSR build ----------
__global__ void hist_kernel(const int* __restrict__ dstrow, int* __restrict__ cnt,
                            int Etot, int E) {
    int i = blockIdx.x * blockDim.x + threadIdx.x;
    if (i >= Etot) return;
    int d = (i < E) ? dstrow[i] : (i - E);
    atomicAdd(&cnt[d], 1);
}

__global__ __launch_bounds__(256) void scan1_kernel(const int* __restrict__ cnt,
                                                    int* __restrict__ out,
                                                    int* __restrict__ btot, int n) {
    __shared__ int s[256];
    int i = blockIdx.x * 256 + threadIdx.x;
    int v = (i < n) ? cnt[i] : 0;
    s[threadIdx.x] = v;
    __syncthreads();
    for (int off = 1; off < 256; off <<= 1) {
        int t = (threadIdx.x >= off) ? s[threadIdx.x - off] : 0;
        __syncthreads();
        s[threadIdx.x] += t;
        __syncthreads();
    }
    if (i < n) out[i] = s[threadIdx.x];
    if (threadIdx.x == 255) btot[blockIdx.x] = s[255];
}
__global__ __launch_bounds__(1024) void scan2_kernel(int* __restrict__ btot, int nb) {
    __shared__ int s[1024];
    int tid = threadIdx.x;
    int v = (tid < nb) ? btot[tid] : 0;
    s[tid] = v;
    __syncthreads();
    for (int off = 1; off < 1024; off <<= 1) {
        int t = (tid >= off) ? s[tid - off] : 0;
        __syncthreads();
        s[tid] += t;
        __syncthreads();
    }
    if (tid < nb) btot[tid] = s[tid] - v;  // exclusive
}
__global__ void scan3_kernel(const int* __restrict__ scanned, const int* __restrict__ btot,
                             int* __restrict__ rowptr, int n) {
    int i = blockIdx.x * 256 + threadIdx.x;
    if (i < n) rowptr[i + 1] = scanned[i] + btot[i >> 8];
    if (i == 0) rowptr[0] = 0;
}

__global__ void fill_kernel(const int* __restrict__ srcrow, const int* __restrict__ dstrow,
                            const int* __restrict__ rowptr, int* __restrict__ pos,
                            int* __restrict__ srcs, int Etot, int E) {
    int i = blockIdx.x * blockDim.x + threadIdx.x;
    if (i >= Etot) return;
    int d = (i < E) ? dstrow[i] : (i - E);
    int s = (i < E) ? srcrow[i] : (i - E);
    int p = atomicAdd(&pos[d], 1);
    srcs[rowptr[d] + p] = s;
}

// ---------- weight pre-transpose: W[K][N] f32 -> Wt[N][K] bf16 ----------
__global__ __launch_bounds__(256) void wconv_kernel(const float* __restrict__ W,
                                                    ushort* __restrict__ Wt, int K, int N) {
    __shared__ float t[32][33];
    int k0 = blockIdx.x * 32, n0 = blockIdx.y * 32;
    int tx = threadIdx.x & 31, ty = threadIdx.x >> 5;  // ty: 0..7
#pragma unroll
    for (int i = 0; i < 32; i += 8)
        t[ty + i][tx] = W[(size_t)(k0 + ty + i) * N + n0 + tx];
    __syncthreads();
#pragma unroll
    for (int i = 0; i < 32; i += 8)
        Wt[(size_t)(n0 + ty + i) * K + k0 + tx] = f2bf(t[tx][ty + i]);
}

// ---------- MFMA GEMM v6: 8-wave 128x128 tile, BK=32, dbuf LDS, gload_lds ----------
// Same staging/swizzle/epilogue as the verified round-1 kernel, redistributed
// over 512 threads: each wave computes a 16x128 strip (1 A-frag, 8 MFMA/step).
// Same grid, same LDS => 3 blocks/CU but 24 waves/CU (was 12) for barrier-
// drain hiding via cross-wave overlap (m114 mechanism).
template <typename TA>
__global__ __launch_bounds__(512) void gemm_mfma2(const TA* __restrict__ A,
                                                  const ushort* __restrict__ Wt,
                                                  ushort* __restrict__ C,
                                                  int M, int K, int N) {
    constexpr bool F32A = (sizeof(TA) == 4);
    constexpr int ASZ = F32A ? 16384 : 8192;  // per-buffer A bytes
    __shared__ __align__(16) unsigned char smem[2 * ASZ + 16384];

    int tid = threadIdx.x;
    int wv = tid >> 6, lane = tid & 63;
    int quad = lane >> 4, mrow = lane & 15;

    // bijective XCD-chunk swizzle (m204)
    int nwg = gridDim.x * gridDim.y;
    int id = blockIdx.y * gridDim.x + blockIdx.x;
    int q8 = nwg >> 3, r8 = nwg & 7;
    int xcd = id & 7, loc = id >> 3;
    int wgid = (xcd < r8 ? xcd * (q8 + 1) : r8 * (q8 + 1) + (xcd - r8) * q8) + loc;
    int n0 = (wgid % gridDim.x) * 128;
    int m0 = (wgid / gridDim.x) * 128;

    f32x4 acc[8] = {};

    auto stageA = [&](int kt, int buf) {
        unsigned char* lb = smem + buf * ASZ;
        if constexpr (F32A) {  // 128 rows x 128B; 512 thr x 16B = 64 rows/iter
#pragma unroll
            for (int q = 0; q < 2; q++) {
                int row = q * 64 + (tid >> 3);
                int gch = (tid & 7) ^ (row & 7);
                int rc = min(m0 + row, M - 1);
                gload_lds16((const float*)A + (size_t)rc * K + kt + gch * 4,
                            lb + q * 8192 + tid * 16);
            }
        } else {  // 128 rows x 64B; one iter covers all
            int row = tid >> 2;
            int gch = (tid & 3) ^ ((row & 3) ^ ((row >> 2) & 1));
            int rc = min(m0 + row, M - 1);
            gload_lds16((const ushort*)A + (size_t)rc * K + kt + gch * 8,
                        lb + tid * 16);
        }
    };
    auto stageB = [&](int kt, int buf) {
        unsigned char* lb = smem + 2 * ASZ + buf * 8192;
        int row = tid >> 2;
        int gch = (tid & 3) ^ ((row & 3) ^ ((row >> 2) & 1));
        gload_lds16(Wt + (size_t)(n0 + row) * K + kt + gch * 8,
                    lb + tid * 16);
    };

    int nsteps = K >> 5;
    stageA(0, 0);
    stageB(0, 0);
    __syncthreads();

    for (int s = 0; s < nsteps; s++) {
        int kt = s << 5;
        if (s + 1 < nsteps) {
            stageA(kt + 32, (s + 1) & 1);
            stageB(kt + 32, (s + 1) & 1);
        }
        const unsigned char* la = smem + (s & 1) * ASZ;
        const unsigned char* lbB = smem + 2 * ASZ + (s & 1) * 8192;

        bf16x8 afrag, bfrag[8];
        {
            int row = wv * 16 + mrow;
            if constexpr (F32A) {
                int f = row & 7;
                float4 x0 = *(const float4*)(la + row * 128 + ((quad * 2 + 0) ^ f) * 16);
                float4 x1 = *(const float4*)(la + row * 128 + ((quad * 2 + 1) ^ f) * 16);
                union { bf16x8 v; ushort u[8]; } t;
                t.u[0] = f2bf(x0.x); t.u[1] = f2bf(x0.y);
                t.u[2] = f2bf(x0.z); t.u[3] = f2bf(x0.w);
                t.u[4] = f2bf(x1.x); t.u[5] = f2bf(x1.y);
                t.u[6] = f2bf(x1.z); t.u[7] = f2bf(x1.w);
                afrag = t.v;
            } else {
                int f = (row & 3) ^ ((row >> 2) & 1);
                afrag = *(const bf16x8*)(la + row * 64 + (quad ^ f) * 16);
            }
        }
#pragma unroll
        for (int c = 0; c < 8; c++) {
            int row = c * 16 + mrow;
            int f = (row & 3) ^ ((row >> 2) & 1);
            bfrag[c] = *(const bf16x8*)(lbB + row * 64 + (quad ^ f) * 16);
        }
#pragma unroll
        for (int c = 0; c < 8; c++)
            acc[c] = __builtin_amdgcn_mfma_f32_16x16x32_bf16(afrag, bfrag[c],
                                                             acc[c], 0, 0, 0);
        __syncthreads();
    }

    // epilogue: C/D layout col=lane&15, row=quad*4+reg
    int col = lane & 15;
#pragma unroll
    for (int c = 0; c < 8; c++) {
#pragma unroll
        for (int reg = 0; reg < 4; reg++) {
            int gm = m0 + wv * 16 + quad * 4 + reg;
            int gn = n0 + c * 16 + col;
            if (gm < M) C[(size_t)gm * N + gn] = f2bf(acc[c][reg]);
        }
    }
}

// ---------- attention logits: one wave per node, bf16 H ----------
template <int VPL>
__global__ __launch_bounds__(256) void attn_wave(const ushort* __restrict__ H,
                                                 const float* __restrict__ asrc,
                                                 const float* __restrict__ adst,
                                                 float* __restrict__ es, float* __restrict__ ed,
                                                 int N) {
    constexpr int HC = VPL * 64;
    int lane = threadIdx.x & 63;
    int node = (blockIdx.x * blockDim.x + threadIdx.x) >> 6;
    if (node >= N) return;
    const ushort* hp = H + (size_t)node * HC + lane * VPL;
    float esum = 0.f, dsum = 0.f;
#pragma unroll
    for (int j = 0; j < VPL; j++) {
        float h = bf2f(hp[j]);
        int ch = lane * VPL + j;
        esum += h * asrc[ch];
        dsum += h * adst[ch];
    }
#pragma unroll
    for (int off = 1; off < 16; off <<= 1) {
        esum += __shfl_xor(esum, off, 64);
        dsum += __shfl_xor(dsum, off, 64);
    }
    if ((lane & 15) == 0) {
        int hh = lane >> 4;
        es[node * 4 + hh] = esum;
        ed[node * 4 + hh] = dsum;
    }
}

// ---------- fused CSR-gather softmax-aggregate + bias + (ELU) + LayerNorm ----------
// round-7 verified: per-edge numerator cache (pbuf) removes the random es
// gather and exp from the weighted-gather inner loop.
template <int VPL>
__global__ __launch_bounds__(256) void agg_gather(
    const ushort* __restrict__ H, const float* __restrict__ es, const float* __restrict__ ed,
    const int* __restrict__ rowptr, const int* __restrict__ srcs, float* pbuf,
    const float* __restrict__ bias, const float* __restrict__ gamma,
    const float* __restrict__ beta, ushort* __restrict__ XoutB, float* __restrict__ XoutF,
    int N, int applyElu) {
    constexpr int HC = VPL * 64;
    int lane = threadIdx.x & 63;
    int node = (blockIdx.x * blockDim.x + threadIdx.x) >> 6;
    if (node >= N) return;
    int base = rowptr[node];
    int deg = rowptr[node + 1] - base;
    float4 ed4 = *(const float4*)&ed[node * 4];

    // pass A: per-edge numerators -> pbuf, accumulate softmax denominator
    float4 sm = make_float4(0.f, 0.f, 0.f, 0.f);
    for (int i = lane; i < deg; i += 64) {
        int s = srcs[base + i];
        float4 e4 = *(const float4*)&es[(size_t)s * 4];
        float4 pv;
        pv.x = __expf(lrelu(e4.x + ed4.x));
        pv.y = __expf(lrelu(e4.y + ed4.y));
        pv.z = __expf(lrelu(e4.z + ed4.z));
        pv.w = __expf(lrelu(e4.w + ed4.w));
        *(float4*)&pbuf[(size_t)(base + i) * 4] = pv;
        sm.x += pv.x; sm.y += pv.y; sm.z += pv.z; sm.w += pv.w;
    }
    sm.x = wave_allred_sum(sm.x); sm.y = wave_allred_sum(sm.y);
    sm.z = wave_allred_sum(sm.z); sm.w = wave_allred_sum(sm.w);

    int hh = lane >> 4;
    float rd_h = 1.f / ((hh == 0) ? sm.x : (hh == 1) ? sm.y : (hh == 2) ? sm.z : sm.w);

    // pass B: weighted gather of bf16 rows; alpha from sequential pbuf reads
    float acc[VPL];
#pragma unroll
    for (int j = 0; j < VPL; j++) acc[j] = 0.f;
    const ushort* Hl = H + lane * VPL;
    const float* pb = pbuf + (size_t)base * 4 + hh;

    int i = 0;
    for (; i + 2 <= deg; i += 2) {
        int s0 = srcs[base + i];
        int s1 = srcs[base + i + 1];
        float a0 = pb[(size_t)i * 4] * rd_h;
        float a1 = pb[(size_t)(i + 1) * 4] * rd_h;
        const ushort* hp0 = Hl + (size_t)s0 * HC;
        const ushort* hp1 = Hl + (size_t)s1 * HC;
        if constexpr (VPL == 4) {
            ushort4 h0 = *(const ushort4*)hp0;
            ushort4 h1 = *(const ushort4*)hp1;
            acc[0] += a0 * bf2f(h0.x) + a1 * bf2f(h1.x);
            acc[1] += a0 * bf2f(h0.y) + a1 * bf2f(h1.y);
            acc[2] += a0 * bf2f(h0.z) + a1 * bf2f(h1.z);
            acc[3] += a0 * bf2f(h0.w) + a1 * bf2f(h1.w);
        } else {
            ushort2 h0 = *(const ushort2*)hp0;
            ushort2 h1 = *(const ushort2*)hp1;
            acc[0] += a0 * bf2f(h0.x) + a1 * bf2f(h1.x);
            acc[1] += a0 * bf2f(h0.y) + a1 * bf2f(h1.y);
        }
    }
    for (; i < deg; i++) {
        int s = srcs[base + i];
        float a = pb[(size_t)i * 4] * rd_h;
        const ushort* hp = Hl + (size_t)s * HC;
        if constexpr (VPL == 4) {
            ushort4 hv = *(const ushort4*)hp;
            acc[0] += a * bf2f(hv.x); acc[1] += a * bf2f(hv.y);
            acc[2] += a * bf2f(hv.z); acc[3] += a * bf2f(hv.w);
        } else {
            ushort2 hv = *(const ushort2*)hp;
            acc[0] += a * bf2f(hv.x); acc[1] += a * bf2f(hv.y);
        }
    }

    // epilogue: bias, optional ELU, LayerNorm
    float v[VPL];
    float s1 = 0.f, s2 = 0.f;
#pragma unroll
    for (int j = 0; j < VPL; j++) {
        int ch = lane * VPL + j;
        float t = acc[j] + bias[ch];
        if (applyElu) t = (t > 0.f) ? t : (__expf(t) - 1.f);
        v[j] = t;
        s1 += t;
        s2 += t * t;
    }
    s1 = wave_allred_sum(s1);
    s2 = wave_allred_sum(s2);
    float mu = s1 / (float)HC;
    float var = s2 / (float)HC - mu * mu;
    float rs = rsqrtf(var + 1e-5f);
#pragma unroll
    for (int j = 0; j < VPL; j++) {
        int ch = lane * VPL + j;
        float o = gamma[ch] * (v[j] - mu) * rs + beta[ch];
        if (XoutF) XoutF[(size_t)node * HC + ch] = o;
        else XoutB[(size_t)node * HC + ch] = f2bf(o);
    }
}

// ---------- graph pooling: sorted-run flush ----------
__global__ __launch_bounds__(128) void gsum_kernel(const float* __restrict__ node_emb,
                                                   const int* __restrict__ batch,
                                                   float* __restrict__ gsum,
                                                   int* __restrict__ gcnt, int N) {
    int start = blockIdx.x * 256;
    if (start >= N) return;
    int end = min(start + 256, N);
    int ch = threadIdx.x;
    float acc = 0.f;
    int runlen = 0;
    int curg = batch[start];
    for (int n = start; n < end; n++) {
        int g = batch[n];
        if (g != curg) {
            atomicAdd(&gsum[curg * 128 + ch], acc);
            if (ch == 0) atomicAdd(&gcnt[curg], runlen);
            acc = 0.f; runlen = 0; curg = g;
        }
        acc += node_emb[(size_t)n * 128 + ch];
        runlen++;
    }
    atomicAdd(&gsum[curg * 128 + ch], acc);
    if (ch == 0) atomicAdd(&gcnt[curg], runlen);
}

__global__ void gfinal_kernel(const float* __restrict__ gsum, const int* __restrict__ gcnt,
                              float* __restrict__ out, int Gn) {
    int i = blockIdx.x * blockDim.x + threadIdx.x;
    if (i >= Gn * 128) return;
    int g = i >> 7;
    out[i] = gsum[i] / fmaxf((float)gcnt[g], 1.f);
}

// ---------- launch ----------
extern "C" void kernel_launch(void* const* d_in, const int* in_sizes, int n_in, void* d_out,
                              int out_size, void* d_ws, size_t ws_size, hipStream_t stream) {
    const float* x = (const float*)d_in[0];
    const int* ei = (const int*)d_in[1];
    const int* batch = (const int*)d_in[2];
    const float* W1 = (const float*)d_in[3];
    const float* as1 = (const float*)d_in[4];
    const float* ad1 = (const float*)d_in[5];
    const float* b1 = (const float*)d_in[6];
    const float* g1 = (const float*)d_in[7];
    const float* be1 = (const float*)d_in[8];
    const float* W2 = (const float*)d_in[9];
    const float* as2 = (const float*)d_in[10];
    const float* ad2 = (const float*)d_in[11];
    const float* b2 = (const float*)d_in[12];
    const float* g2 = (const float*)d_in[13];
    const float* be2 = (const float*)d_in[14];
    const float* W3 = (const float*)d_in[15];
    const float* as3 = (const float*)d_in[16];
    const float* ad3 = (const float*)d_in[17];
    const float* b3 = (const float*)d_in[18];
    const float* g3 = (const float*)d_in[19];
    const float* be3 = (const float*)d_in[20];

    int N = in_sizes[2];
    int E = in_sizes[1] / 2;
    int Etot = E + N;

    char* w = (char*)d_ws;
    size_t off = 0;
    auto alloc = [&](size_t bytes) -> void* {
        void* p = w + off;
        off += (bytes + 255) & ~(size_t)255;
        return p;
    };
    int* cnt = (int*)alloc((size_t)N * 4);       // | zero region
    int* pos = (int*)alloc((size_t)N * 4);       // |
    float* gsum = (float*)alloc(64 * 128 * 4);   // |
    int* gcnt = (int*)alloc(64 * 4);             // |
    size_t zbytes = off;
    int* scantmp = (int*)alloc((size_t)N * 4);
    int* btot = (int*)alloc(1024 * 4);
    int* rowptr = (int*)alloc((size_t)(N + 1) * 4);
    int* srcs = (int*)alloc((size_t)Etot * 4);
    float* es = (float*)alloc((size_t)N * 16);
    float* ed = (float*)alloc((size_t)N * 16);
    float* pbuf = (float*)alloc((size_t)Etot * 16);    // per-edge numerator cache
    ushort* Hb = (ushort*)alloc((size_t)N * 256 * 2);  // bf16 H
    ushort* Xb = (ushort*)alloc((size_t)N * 256 * 2);  // bf16 X (inter-layer)
    ushort* wt1 = (ushort*)alloc((size_t)768 * 256 * 2);  // W^T bf16 [N][K]
    ushort* wt2 = (ushort*)alloc((size_t)256 * 256 * 2);
    ushort* wt3 = (ushort*)alloc((size_t)256 * 128 * 2);

    hipMemsetAsync(d_ws, 0, zbytes, stream);

    const int* srcrow = ei;
    const int* dstrow = ei + E;

    // weight pre-transpose (tiny)
    wconv_kernel<<<dim3(768 / 32, 256 / 32), 256, 0, stream>>>(W1, wt1, 768, 256);
    wconv_kernel<<<dim3(256 / 32, 256 / 32), 256, 0, stream>>>(W2, wt2, 256, 256);
    wconv_kernel<<<dim3(256 / 32, 128 / 32), 256, 0, stream>>>(W3, wt3, 256, 128);

    int eb = (Etot + 255) / 256;
    int nb = (N + 255) / 256;
    hist_kernel<<<eb, 256, 0, stream>>>(dstrow, cnt, Etot, E);
    scan1_kernel<<<nb, 256, 0, stream>>>(cnt, scantmp, btot, N);
    scan2_kernel<<<1, 1024, 0, stream>>>(btot, nb);
    scan3_kernel<<<nb, 256, 0, stream>>>(scantmp, btot, rowptr, N);
    fill_kernel<<<eb, 256, 0, stream>>>(srcrow, dstrow, rowptr, pos, srcs, Etot, E);

    int mT = (N + 127) / 128;
    int nodeWaveBlocks = (N + 3) / 4;

    float* out_node = (float*)d_out;                     // [N,128] f32
    float* out_graph = (float*)d_out + (size_t)N * 128;  // [64,128] f32

    // ---- layer 1: 768 -> 256 ----
    gemm_mfma2<float><<<dim3(2, mT), 512, 0, stream>>>(x, wt1, Hb, N, 768, 256);
    attn_wave<4><<<nodeWaveBlocks, 256, 0, stream>>>(Hb, as1, ad1, es, ed, N);
    agg_gather<4><<<nodeWaveBlocks, 256, 0, stream>>>(Hb, es, ed, rowptr, srcs, pbuf,
                                                      b1, g1, be1, Xb, nullptr, N, 1);
    // ---- layer 2: 256 -> 256 ----
    gemm_mfma2<ushort><<<dim3(2, mT), 512, 0, stream>>>(Xb, wt2, Hb, N, 256, 256);
    attn_wave<4><<<nodeWaveBlocks, 256, 0, stream>>>(Hb, as2, ad2, es, ed, N);
    agg_gather<4><<<nodeWaveBlocks, 256, 0, stream>>>(Hb, es, ed, rowptr, srcs, pbuf,
                                                      b2, g2, be2, Xb, nullptr, N, 1);
    // ---- layer 3: 256 -> 128 (no ELU; node_emb -> d_out f32) ----
    gemm_mfma2<ushort><<<dim3(1, mT), 512, 0, stream>>>(Xb, wt3, Hb, N, 256, 128);
    attn_wave<2><<<nodeWaveBlocks, 256, 0, stream>>>(Hb, as3, ad3, es, ed, N);
    agg_gather<2><<<nodeWaveBlocks, 256, 0, stream>>>(Hb, es, ed, rowptr, srcs, pbuf,
                                                      b3, g3, be3, nullptr, out_node, N, 0);
    // ---- graph pooling ----
    gsum_kernel<<<(N + 255) / 256, 128, 0, stream>>>(out_node, batch, gsum, gcnt, N);
    gfinal_kernel<<<(64 * 128 + 255) / 256, 256, 0, stream>>>(gsum, gcnt, out_graph, 64);
}

// Round 9
// 744.054 us; speedup vs baseline: 1.0927x; 1.0316x over previous
//
#include <hip/hip_runtime.h>
#include <math.h>

// ---------- helpers ----------
__device__ __forceinline__ float lrelu(float v) { return v > 0.f ? v : 0.2f * v; }
__device__ __forceinline__ float bf2f(ushort u) {
    return __uint_as_float(((unsigned int)u) << 16);
}
__device__ __forceinline__ ushort f2bf(float f) {
    unsigned int x = __float_as_uint(f);
    return (ushort)((x + 0x7fffu + ((x >> 16) & 1u)) >> 16);
}
__device__ __forceinline__ float wave_allred_sum(float v) {
#pragma unroll
    for (int off = 1; off < 64; off <<= 1) v += __shfl_xor(v, off, 64);
    return v;
}

typedef short bf16x8 __attribute__((ext_vector_type(8)));
typedef float f32x4 __attribute__((ext_vector_type(4)));

typedef const __attribute__((address_space(1))) void* gas_ptr;
typedef __attribute__((address_space(3))) void* las_ptr;
__device__ __forceinline__ void gload_lds16(const void* g, void* l) {
    __builtin_amdgcn_global_load_lds((gas_ptr)g, (las_ptr)l, 16, 0, 0);
}

// ---------- CSR build ----------
__global__ void hist_kernel(const int* __restrict__ dstrow, int* __restrict__ cnt,
                            int Etot, int E) {
    int i = blockIdx.x * blockDim.x + threadIdx.x;
    if (i >= Etot) return;
    int d = (i < E) ? dstrow[i] : (i - E);
    atomicAdd(&cnt[d], 1);
}

__global__ __launch_bounds__(256) void scan1_kernel(const int* __restrict__ cnt,
                                                    int* __restrict__ out,
                                                    int* __restrict__ btot, int n) {
    __shared__ int s[256];
    int i = blockIdx.x * 256 + threadIdx.x;
    int v = (i < n) ? cnt[i] : 0;
    s[threadIdx.x] = v;
    __syncthreads();
    for (int off = 1; off < 256; off <<= 1) {
        int t = (threadIdx.x >= off) ? s[threadIdx.x - off] : 0;
        __syncthreads();
        s[threadIdx.x] += t;
        __syncthreads();
    }
    if (i < n) out[i] = s[threadIdx.x];
    if (threadIdx.x == 255) btot[blockIdx.x] = s[255];
}
__global__ __launch_bounds__(1024) void scan2_kernel(int* __restrict__ btot, int nb) {
    __shared__ int s[1024];
    int tid = threadIdx.x;
    int v = (tid < nb) ? btot[tid] : 0;
    s[tid] = v;
    __syncthreads();
    for (int off = 1; off < 1024; off <<= 1) {
        int t = (tid >= off) ? s[tid - off] : 0;
        __syncthreads();
        s[tid] += t;
        __syncthreads();
    }
    if (tid < nb) btot[tid] = s[tid] - v;  // exclusive
}
__global__ void scan3_kernel(const int* __restrict__ scanned, const int* __restrict__ btot,
                             int* __restrict__ rowptr, int n) {
    int i = blockIdx.x * 256 + threadIdx.x;
    if (i < n) rowptr[i + 1] = scanned[i] + btot[i >> 8];
    if (i == 0) rowptr[0] = 0;
}

__global__ void fill_kernel(const int* __restrict__ srcrow, const int* __restrict__ dstrow,
                            const int* __restrict__ rowptr, int* __restrict__ pos,
                            int* __restrict__ srcs, int Etot, int E) {
    int i = blockIdx.x * blockDim.x + threadIdx.x;
    if (i >= Etot) return;
    int d = (i < E) ? dstrow[i] : (i - E);
    int s = (i < E) ? srcrow[i] : (i - E);
    int p = atomicAdd(&pos[d], 1);
    srcs[rowptr[d] + p] = s;
}

// ---------- weight pre-transpose: W[K][N] f32 -> Wt[N][K] bf16 ----------
__global__ __launch_bounds__(256) void wconv_kernel(const float* __restrict__ W,
                                                    ushort* __restrict__ Wt, int K, int N) {
    __shared__ float t[32][33];
    int k0 = blockIdx.x * 32, n0 = blockIdx.y * 32;
    int tx = threadIdx.x & 31, ty = threadIdx.x >> 5;  // ty: 0..7
#pragma unroll
    for (int i = 0; i < 32; i += 8)
        t[ty + i][tx] = W[(size_t)(k0 + ty + i) * N + n0 + tx];
    __syncthreads();
#pragma unroll
    for (int i = 0; i < 32; i += 8)
        Wt[(size_t)(n0 + ty + i) * K + k0 + tx] = f2bf(t[tx][ty + i]);
}

// ---------- MFMA GEMM v6 (round-8 verified): 8-wave 128x128 tile ----------
template <typename TA>
__global__ __launch_bounds__(512) void gemm_mfma2(const TA* __restrict__ A,
                                                  const ushort* __restrict__ Wt,
                                                  ushort* __restrict__ C,
                                                  int M, int K, int N) {
    constexpr bool F32A = (sizeof(TA) == 4);
    constexpr int ASZ = F32A ? 16384 : 8192;  // per-buffer A bytes
    __shared__ __align__(16) unsigned char smem[2 * ASZ + 16384];

    int tid = threadIdx.x;
    int wv = tid >> 6, lane = tid & 63;
    int quad = lane >> 4, mrow = lane & 15;

    // bijective XCD-chunk swizzle (m204)
    int nwg = gridDim.x * gridDim.y;
    int id = blockIdx.y * gridDim.x + blockIdx.x;
    int q8 = nwg >> 3, r8 = nwg & 7;
    int xcd = id & 7, loc = id >> 3;
    int wgid = (xcd < r8 ? xcd * (q8 + 1) : r8 * (q8 + 1) + (xcd - r8) * q8) + loc;
    int n0 = (wgid % gridDim.x) * 128;
    int m0 = (wgid / gridDim.x) * 128;

    f32x4 acc[8] = {};

    auto stageA = [&](int kt, int buf) {
        unsigned char* lb = smem + buf * ASZ;
        if constexpr (F32A) {  // 128 rows x 128B; 512 thr x 16B = 64 rows/iter
#pragma unroll
            for (int q = 0; q < 2; q++) {
                int row = q * 64 + (tid >> 3);
                int gch = (tid & 7) ^ (row & 7);
                int rc = min(m0 + row, M - 1);
                gload_lds16((const float*)A + (size_t)rc * K + kt + gch * 4,
                            lb + q * 8192 + tid * 16);
            }
        } else {  // 128 rows x 64B; one iter covers all
            int row = tid >> 2;
            int gch = (tid & 3) ^ ((row & 3) ^ ((row >> 2) & 1));
            int rc = min(m0 + row, M - 1);
            gload_lds16((const ushort*)A + (size_t)rc * K + kt + gch * 8,
                        lb + tid * 16);
        }
    };
    auto stageB = [&](int kt, int buf) {
        unsigned char* lb = smem + 2 * ASZ + buf * 8192;
        int row = tid >> 2;
        int gch = (tid & 3) ^ ((row & 3) ^ ((row >> 2) & 1));
        gload_lds16(Wt + (size_t)(n0 + row) * K + kt + gch * 8,
                    lb + tid * 16);
    };

    int nsteps = K >> 5;
    stageA(0, 0);
    stageB(0, 0);
    __syncthreads();

    for (int s = 0; s < nsteps; s++) {
        int kt = s << 5;
        if (s + 1 < nsteps) {
            stageA(kt + 32, (s + 1) & 1);
            stageB(kt + 32, (s + 1) & 1);
        }
        const unsigned char* la = smem + (s & 1) * ASZ;
        const unsigned char* lbB = smem + 2 * ASZ + (s & 1) * 8192;

        bf16x8 afrag, bfrag[8];
        {
            int row = wv * 16 + mrow;
            if constexpr (F32A) {
                int f = row & 7;
                float4 x0 = *(const float4*)(la + row * 128 + ((quad * 2 + 0) ^ f) * 16);
                float4 x1 = *(const float4*)(la + row * 128 + ((quad * 2 + 1) ^ f) * 16);
                union { bf16x8 v; ushort u[8]; } t;
                t.u[0] = f2bf(x0.x); t.u[1] = f2bf(x0.y);
                t.u[2] = f2bf(x0.z); t.u[3] = f2bf(x0.w);
                t.u[4] = f2bf(x1.x); t.u[5] = f2bf(x1.y);
                t.u[6] = f2bf(x1.z); t.u[7] = f2bf(x1.w);
                afrag = t.v;
            } else {
                int f = (row & 3) ^ ((row >> 2) & 1);
                afrag = *(const bf16x8*)(la + row * 64 + (quad ^ f) * 16);
            }
        }
#pragma unroll
        for (int c = 0; c < 8; c++) {
            int row = c * 16 + mrow;
            int f = (row & 3) ^ ((row >> 2) & 1);
            bfrag[c] = *(const bf16x8*)(lbB + row * 64 + (quad ^ f) * 16);
        }
#pragma unroll
        for (int c = 0; c < 8; c++)
            acc[c] = __builtin_amdgcn_mfma_f32_16x16x32_bf16(afrag, bfrag[c],
                                                             acc[c], 0, 0, 0);
        __syncthreads();
    }

    // epilogue: C/D layout col=lane&15, row=quad*4+reg
    int col = lane & 15;
#pragma unroll
    for (int c = 0; c < 8; c++) {
#pragma unroll
        for (int reg = 0; reg < 4; reg++) {
            int gm = m0 + wv * 16 + quad * 4 + reg;
            int gn = n0 + c * 16 + col;
            if (gm < M) C[(size_t)gm * N + gn] = f2bf(acc[c][reg]);
        }
    }
}

// ---------- attention logits: one wave per node, bf16 H ----------
template <int VPL>
__global__ __launch_bounds__(256) void attn_wave(const ushort* __restrict__ H,
                                                 const float* __restrict__ asrc,
                                                 const float* __restrict__ adst,
                                                 float* __restrict__ es, float* __restrict__ ed,
                                                 int N) {
    constexpr int HC = VPL * 64;
    int lane = threadIdx.x & 63;
    int node = (blockIdx.x * blockDim.x + threadIdx.x) >> 6;
    if (node >= N) return;
    const ushort* hp = H + (size_t)node * HC + lane * VPL;
    float esum = 0.f, dsum = 0.f;
#pragma unroll
    for (int j = 0; j < VPL; j++) {
        float h = bf2f(hp[j]);
        int ch = lane * VPL + j;
        esum += h * asrc[ch];
        dsum += h * adst[ch];
    }
#pragma unroll
    for (int off = 1; off < 16; off <<= 1) {
        esum += __shfl_xor(esum, off, 64);
        dsum += __shfl_xor(dsum, off, 64);
    }
    if ((lane & 15) == 0) {
        int hh = lane >> 4;
        es[node * 4 + hh] = esum;
        ed[node * 4 + hh] = dsum;
    }
}

// ---------- fused CSR-gather softmax-aggregate + bias + (ELU) + LayerNorm ----------
// round-7 pbuf cache + round-9 change: pass-B unrolled by 4 — four independent
// edge chains in flight per wave (was 2) to cover the random H-row latency.
template <int VPL>
__global__ __launch_bounds__(256) void agg_gather(
    const ushort* __restrict__ H, const float* __restrict__ es, const float* __restrict__ ed,
    const int* __restrict__ rowptr, const int* __restrict__ srcs, float* pbuf,
    const float* __restrict__ bias, const float* __restrict__ gamma,
    const float* __restrict__ beta, ushort* __restrict__ XoutB, float* __restrict__ XoutF,
    int N, int applyElu) {
    constexpr int HC = VPL * 64;
    int lane = threadIdx.x & 63;
    int node = (blockIdx.x * blockDim.x + threadIdx.x) >> 6;
    if (node >= N) return;
    int base = rowptr[node];
    int deg = rowptr[node + 1] - base;
    float4 ed4 = *(const float4*)&ed[node * 4];

    // pass A: per-edge numerators -> pbuf, accumulate softmax denominator
    float4 sm = make_float4(0.f, 0.f, 0.f, 0.f);
    for (int i = lane; i < deg; i += 64) {
        int s = srcs[base + i];
        float4 e4 = *(const float4*)&es[(size_t)s * 4];
        float4 pv;
        pv.x = __expf(lrelu(e4.x + ed4.x));
        pv.y = __expf(lrelu(e4.y + ed4.y));
        pv.z = __expf(lrelu(e4.z + ed4.z));
        pv.w = __expf(lrelu(e4.w + ed4.w));
        *(float4*)&pbuf[(size_t)(base + i) * 4] = pv;
        sm.x += pv.x; sm.y += pv.y; sm.z += pv.z; sm.w += pv.w;
    }
    sm.x = wave_allred_sum(sm.x); sm.y = wave_allred_sum(sm.y);
    sm.z = wave_allred_sum(sm.z); sm.w = wave_allred_sum(sm.w);

    int hh = lane >> 4;
    float rd_h = 1.f / ((hh == 0) ? sm.x : (hh == 1) ? sm.y : (hh == 2) ? sm.z : sm.w);

    // pass B: weighted gather of bf16 rows; 4 independent chains in flight
    float acc[VPL];
#pragma unroll
    for (int j = 0; j < VPL; j++) acc[j] = 0.f;
    const ushort* Hl = H + lane * VPL;
    const float* pb = pbuf + (size_t)base * 4 + hh;

    int i = 0;
    for (; i + 4 <= deg; i += 4) {
        int s0 = srcs[base + i];
        int s1 = srcs[base + i + 1];
        int s2 = srcs[base + i + 2];
        int s3 = srcs[base + i + 3];
        float a0 = pb[(size_t)i * 4] * rd_h;
        float a1 = pb[(size_t)(i + 1) * 4] * rd_h;
        float a2 = pb[(size_t)(i + 2) * 4] * rd_h;
        float a3 = pb[(size_t)(i + 3) * 4] * rd_h;
        const ushort* hp0 = Hl + (size_t)s0 * HC;
        const ushort* hp1 = Hl + (size_t)s1 * HC;
        const ushort* hp2 = Hl + (size_t)s2 * HC;
        const ushort* hp3 = Hl + (size_t)s3 * HC;
        if constexpr (VPL == 4) {
            ushort4 h0 = *(const ushort4*)hp0;
            ushort4 h1 = *(const ushort4*)hp1;
            ushort4 h2 = *(const ushort4*)hp2;
            ushort4 h3 = *(const ushort4*)hp3;
            acc[0] += a0 * bf2f(h0.x) + a1 * bf2f(h1.x) + a2 * bf2f(h2.x) + a3 * bf2f(h3.x);
            acc[1] += a0 * bf2f(h0.y) + a1 * bf2f(h1.y) + a2 * bf2f(h2.y) + a3 * bf2f(h3.y);
            acc[2] += a0 * bf2f(h0.z) + a1 * bf2f(h1.z) + a2 * bf2f(h2.z) + a3 * bf2f(h3.z);
            acc[3] += a0 * bf2f(h0.w) + a1 * bf2f(h1.w) + a2 * bf2f(h2.w) + a3 * bf2f(h3.w);
        } else {
            ushort2 h0 = *(const ushort2*)hp0;
            ushort2 h1 = *(const ushort2*)hp1;
            ushort2 h2 = *(const ushort2*)hp2;
            ushort2 h3 = *(const ushort2*)hp3;
            acc[0] += a0 * bf2f(h0.x) + a1 * bf2f(h1.x) + a2 * bf2f(h2.x) + a3 * bf2f(h3.x);
            acc[1] += a0 * bf2f(h0.y) + a1 * bf2f(h1.y) + a2 * bf2f(h2.y) + a3 * bf2f(h3.y);
        }
    }
    for (; i < deg; i++) {
        int s = srcs[base + i];
        float a = pb[(size_t)i * 4] * rd_h;
        const ushort* hp = Hl + (size_t)s * HC;
        if constexpr (VPL == 4) {
            ushort4 hv = *(const ushort4*)hp;
            acc[0] += a * bf2f(hv.x); acc[1] += a * bf2f(hv.y);
            acc[2] += a * bf2f(hv.z); acc[3] += a * bf2f(hv.w);
        } else {
            ushort2 hv = *(const ushort2*)hp;
            acc[0] += a * bf2f(hv.x); acc[1] += a * bf2f(hv.y);
        }
    }

    // epilogue: bias, optional ELU, LayerNorm
    float v[VPL];
    float s1 = 0.f, s2 = 0.f;
#pragma unroll
    for (int j = 0; j < VPL; j++) {
        int ch = lane * VPL + j;
        float t = acc[j] + bias[ch];
        if (applyElu) t = (t > 0.f) ? t : (__expf(t) - 1.f);
        v[j] = t;
        s1 += t;
        s2 += t * t;
    }
    s1 = wave_allred_sum(s1);
    s2 = wave_allred_sum(s2);
    float mu = s1 / (float)HC;
    float var = s2 / (float)HC - mu * mu;
    float rs = rsqrtf(var + 1e-5f);
#pragma unroll
    for (int j = 0; j < VPL; j++) {
        int ch = lane * VPL + j;
        float o = gamma[ch] * (v[j] - mu) * rs + beta[ch];
        if (XoutF) XoutF[(size_t)node * HC + ch] = o;
        else XoutB[(size_t)node * HC + ch] = f2bf(o);
    }
}

// ---------- graph pooling: sorted-run flush ----------
__global__ __launch_bounds__(128) void gsum_kernel(const float* __restrict__ node_emb,
                                                   const int* __restrict__ batch,
                                                   float* __restrict__ gsum,
                                                   int* __restrict__ gcnt, int N) {
    int start = blockIdx.x * 256;
    if (start >= N) return;
    int end = min(start + 256, N);
    int ch = threadIdx.x;
    float acc = 0.f;
    int runlen = 0;
    int curg = batch[start];
    for (int n = start; n < end; n++) {
        int g = batch[n];
        if (g != curg) {
            atomicAdd(&gsum[curg * 128 + ch], acc);
            if (ch == 0) atomicAdd(&gcnt[curg], runlen);
            acc = 0.f; runlen = 0; curg = g;
        }
        acc += node_emb[(size_t)n * 128 + ch];
        runlen++;
    }
    atomicAdd(&gsum[curg * 128 + ch], acc);
    if (ch == 0) atomicAdd(&gcnt[curg], runlen);
}

__global__ void gfinal_kernel(const float* __restrict__ gsum, const int* __restrict__ gcnt,
                              float* __restrict__ out, int Gn) {
    int i = blockIdx.x * blockDim.x + threadIdx.x;
    if (i >= Gn * 128) return;
    int g = i >> 7;
    out[i] = gsum[i] / fmaxf((float)gcnt[g], 1.f);
}

// ---------- launch ----------
extern "C" void kernel_launch(void* const* d_in, const int* in_sizes, int n_in, void* d_out,
                              int out_size, void* d_ws, size_t ws_size, hipStream_t stream) {
    const float* x = (const float*)d_in[0];
    const int* ei = (const int*)d_in[1];
    const int* batch = (const int*)d_in[2];
    const float* W1 = (const float*)d_in[3];
    const float* as1 = (const float*)d_in[4];
    const float* ad1 = (const float*)d_in[5];
    const float* b1 = (const float*)d_in[6];
    const float* g1 = (const float*)d_in[7];
    const float* be1 = (const float*)d_in[8];
    const float* W2 = (const float*)d_in[9];
    const float* as2 = (const float*)d_in[10];
    const float* ad2 = (const float*)d_in[11];
    const float* b2 = (const float*)d_in[12];
    const float* g2 = (const float*)d_in[13];
    const float* be2 = (const float*)d_in[14];
    const float* W3 = (const float*)d_in[15];
    const float* as3 = (const float*)d_in[16];
    const float* ad3 = (const float*)d_in[17];
    const float* b3 = (const float*)d_in[18];
    const float* g3 = (const float*)d_in[19];
    const float* be3 = (const float*)d_in[20];

    int N = in_sizes[2];
    int E = in_sizes[1] / 2;
    int Etot = E + N;

    char* w = (char*)d_ws;
    size_t off = 0;
    auto alloc = [&](size_t bytes) -> void* {
        void* p = w + off;
        off += (bytes + 255) & ~(size_t)255;
        return p;
    };
    int* cnt = (int*)alloc((size_t)N * 4);       // | zero region
    int* pos = (int*)alloc((size_t)N * 4);       // |
    float* gsum = (float*)alloc(64 * 128 * 4);   // |
    int* gcnt = (int*)alloc(64 * 4);             // |
    size_t zbytes = off;
    int* scantmp = (int*)alloc((size_t)N * 4);
    int* btot = (int*)alloc(1024 * 4);
    int* rowptr = (int*)alloc((size_t)(N + 1) * 4);
    int* srcs = (int*)alloc((size_t)Etot * 4);
    float* es = (float*)alloc((size_t)N * 16);
    float* ed = (float*)alloc((size_t)N * 16);
    float* pbuf = (float*)alloc((size_t)Etot * 16);    // per-edge numerator cache
    ushort* Hb = (ushort*)alloc((size_t)N * 256 * 2);  // bf16 H
    ushort* Xb = (ushort*)alloc((size_t)N * 256 * 2);  // bf16 X (inter-layer)
    ushort* wt1 = (ushort*)alloc((size_t)768 * 256 * 2);  // W^T bf16 [N][K]
    ushort* wt2 = (ushort*)alloc((size_t)256 * 256 * 2);
    ushort* wt3 = (ushort*)alloc((size_t)256 * 128 * 2);

    hipMemsetAsync(d_ws, 0, zbytes, stream);

    const int* srcrow = ei;
    const int* dstrow = ei + E;

    // weight pre-transpose (tiny)
    wconv_kernel<<<dim3(768 / 32, 256 / 32), 256, 0, stream>>>(W1, wt1, 768, 256);
    wconv_kernel<<<dim3(256 / 32, 256 / 32), 256, 0, stream>>>(W2, wt2, 256, 256);
    wconv_kernel<<<dim3(256 / 32, 128 / 32), 256, 0, stream>>>(W3, wt3, 256, 128);

    int eb = (Etot + 255) / 256;
    int nb = (N + 255) / 256;
    hist_kernel<<<eb, 256, 0, stream>>>(dstrow, cnt, Etot, E);
    scan1_kernel<<<nb, 256, 0, stream>>>(cnt, scantmp, btot, N);
    scan2_kernel<<<1, 1024, 0, stream>>>(btot, nb);
    scan3_kernel<<<nb, 256, 0, stream>>>(scantmp, btot, rowptr, N);
    fill_kernel<<<eb, 256, 0, stream>>>(srcrow, dstrow, rowptr, pos, srcs, Etot, E);

    int mT = (N + 127) / 128;
    int nodeWaveBlocks = (N + 3) / 4;

    float* out_node = (float*)d_out;                     // [N,128] f32
    float* out_graph = (float*)d_out + (size_t)N * 128;  // [64,128] f32

    // ---- layer 1: 768 -> 256 ----
    gemm_mfma2<float><<<dim3(2, mT), 512, 0, stream>>>(x, wt1, Hb, N, 768, 256);
    attn_wave<4><<<nodeWaveBlocks, 256, 0, stream>>>(Hb, as1, ad1, es, ed, N);
    agg_gather<4><<<nodeWaveBlocks, 256, 0, stream>>>(Hb, es, ed, rowptr, srcs, pbuf,
                                                      b1, g1, be1, Xb, nullptr, N, 1);
    // ---- layer 2: 256 -> 256 ----
    gemm_mfma2<ushort><<<dim3(2, mT), 512, 0, stream>>>(Xb, wt2, Hb, N, 256, 256);
    attn_wave<4><<<nodeWaveBlocks, 256, 0, stream>>>(Hb, as2, ad2, es, ed, N);
    agg_gather<4><<<nodeWaveBlocks, 256, 0, stream>>>(Hb, es, ed, rowptr, srcs, pbuf,
                                                      b2, g2, be2, Xb, nullptr, N, 1);
    // ---- layer 3: 256 -> 128 (no ELU; node_emb -> d_out f32) ----
    gemm_mfma2<ushort><<<dim3(1, mT), 512, 0, stream>>>(Xb, wt3, Hb, N, 256, 128);
    attn_wave<2><<<nodeWaveBlocks, 256, 0, stream>>>(Hb, as3, ad3, es, ed, N);
    agg_gather<2><<<nodeWaveBlocks, 256, 0, stream>>>(Hb, es, ed, rowptr, srcs, pbuf,
                                                      b3, g3, be3, nullptr, out_node, N, 0);
    // ---- graph pooling ----
    gsum_kernel<<<(N + 255) / 256, 128, 0, stream>>>(out_node, batch, gsum, gcnt, N);
    gfinal_kernel<<<(64 * 128 + 255) / 256, 256, 0, stream>>>(gsum, gcnt, out_graph, 64);
}